// Round 7
// baseline (339.534 us; speedup 1.0000x reference)
//
#include <hip/hip_runtime.h>

// LightGCN propagation: 3x SpMM over fixed COO graph + batched dot epilogue.
// R7: spmm re-laid as 4 groups x 16 lanes (uint2/lane, 4x unroll = 16 edges
// in flight). Rationale: avg degree 16 -> one main-loop iteration per wave,
// so the old 8-group epilogue (24 ds_swizzle + 24 add) dominated VALU. New
// epilogue = 2 shfl rounds x 4 floats. rowinfo packed start|deg<<22 (one
// prologue load). p2b dispatch removed: p3/p4 inline the 256-bucket scan.
// bf16 row storage (R5): compulsory fabric traffic = 8 XCD x 19.2MB.

#define N_USERS 50000
#define N_ITEMS 100000
#define N_NODES 150000
#define N_EDGES 2400000
#define DIM 64
#define BATCH 4096

#define CHUNKS 512
#define CHUNK_EDGES 4688   // 512*4688 = 2400256 >= N_EDGES
#define KB 256             // coarse buckets
#define NPB 586            // nodes per bucket; 256*586 = 150016 >= N_NODES
#define CONVB ((N_NODES * DIM / 4) / 256)   // 9375 conv blocks

typedef unsigned int uint;
typedef float v2f __attribute__((ext_vector_type(2)));

__device__ __forceinline__ uint pack_bf16(float a, float b) {
    uint ua = __float_as_uint(a), ub = __float_as_uint(b);
    ua = (ua + 0x7FFFu + ((ua >> 16) & 1u)) >> 16;   // RTNE
    ub = (ub + 0x7FFFu + ((ub >> 16) & 1u)) >> 16;
    return ua | (ub << 16);
}

__device__ __forceinline__ v2f unpack_bf16x2(uint w) {
    v2f r;
    r.x = __uint_as_float(w << 16);
    r.y = __uint_as_float(w & 0xFFFF0000u);
    return r;
}

// Fused P1 + conv: blocks [0,CHUNKS) per-chunk coarse histogram;
// blocks [CHUNKS, CHUNKS+CONVB) convert fp32 tables -> bf16 concat t0.
__global__ __launch_bounds__(256) void p1_hist_conv(
        const int* __restrict__ dst, int* __restrict__ hist,
        const float* __restrict__ emb_user, const float* __restrict__ emb_item,
        uint2* __restrict__ t0) {
    int t = threadIdx.x;
    if (blockIdx.x < CHUNKS) {
        __shared__ int h[KB];
        int c = blockIdx.x;
        h[t] = 0;
        __syncthreads();
        int base = c * CHUNK_EDGES;
        for (int i = t; i < CHUNK_EDGES; i += 256) {
            int e = base + i;
            if (e < N_EDGES) atomicAdd(&h[(unsigned)dst[e] / NPB], 1);
        }
        __syncthreads();
        hist[t * CHUNKS + c] = h[t];   // bucket-major
    } else {
        int i = (blockIdx.x - CHUNKS) * 256 + t;       // float4 index, 2.4M total
        const int userN4 = N_USERS * DIM / 4;          // 800000
        float4 v;
        if (i < userN4) v = ((const float4*)emb_user)[i];
        else            v = ((const float4*)emb_item)[i - userN4];
        t0[i] = make_uint2(pack_bf16(v.x, v.y), pack_bf16(v.z, v.w));
    }
}

// P2a: per-bucket exclusive scan over its 512 chunk counts; emit totals.
__global__ __launch_bounds__(256) void p2a_scan(int* __restrict__ hist,
                                                int* __restrict__ tot) {
    int b = blockIdx.x, t = threadIdx.x;
    int i0 = b * CHUNKS + 2 * t;
    int v0 = hist[i0], v1 = hist[i0 + 1];
    int s = v0 + v1;
    __shared__ int sm[256];
    sm[t] = s;
    __syncthreads();
    for (int o = 1; o < 256; o <<= 1) {
        int add = (t >= o) ? sm[t - o] : 0;
        __syncthreads();
        sm[t] += add;
        __syncthreads();
    }
    int excl = sm[t] - s;
    hist[i0] = excl;
    hist[i0 + 1] = excl + v0;
    if (t == 255) tot[b] = excl + s;
}

// P3: coarse partition into block-owned per-bucket runs. Inlines the
// 256-bucket-total scan (replaces the old p2b dispatch).
// Payload packed: x = src | dst_local<<18, y = val bits.
__global__ __launch_bounds__(256) void p3_part(const int* __restrict__ src,
                                               const int* __restrict__ dstA,
                                               const float* __restrict__ vals,
                                               const int* __restrict__ hist,
                                               const int* __restrict__ tot,
                                               int2* __restrict__ coarse) {
    __shared__ int cur[KB];
    __shared__ int sm[KB];
    int c = blockIdx.x, t = threadIdx.x;
    int v = tot[t];
    sm[t] = v;
    __syncthreads();
    for (int o = 1; o < 256; o <<= 1) {
        int add = (t >= o) ? sm[t - o] : 0;
        __syncthreads();
        sm[t] += add;
        __syncthreads();
    }
    cur[t] = (sm[t] - v) + hist[t * CHUNKS + c];   // bucket_base + chunk offset
    __syncthreads();
    int base = c * CHUNK_EDGES;
    for (int i = t; i < CHUNK_EDGES; i += 256) {
        int e = base + i;
        if (e < N_EDGES) {
            int d = dstA[e];
            int b = (int)((unsigned)d / NPB);
            int dl = d - b * NPB;
            int p = atomicAdd(&cur[b], 1);
            coarse[p] = make_int2(src[e] | (dl << 18), __float_as_int(vals[e]));
        }
    }
}

// P4: fine sort within each bucket + emit packed rowinfo (start | deg<<22).
// 1024 threads; inlines the bucket-total scan for base/ne.
__global__ __launch_bounds__(1024) void p4_fine(const int2* __restrict__ coarse,
                                                const int* __restrict__ tot,
                                                int2* __restrict__ epair,
                                                uint* __restrict__ rowinfo) {
    int k = blockIdx.x, t = threadIdx.x;
    __shared__ int cnt[768];
    __shared__ int rs[768];
    __shared__ int sm[1024];
    __shared__ int s_base;
    // bucket_base scan (first 256 threads)
    if (t < KB) sm[t] = tot[t];
    __syncthreads();
    for (int o = 1; o < KB; o <<= 1) {
        int add = 0;
        if (t < KB && t >= o) add = sm[t - o];
        __syncthreads();
        if (t < KB) sm[t] += add;
        __syncthreads();
    }
    if (t == 0) s_base = sm[k] - tot[k];
    if (t < 768) cnt[t] = 0;
    __syncthreads();
    int base = s_base;
    int ne = tot[k];
    for (int i = t; i < ne; i += 1024)
        atomicAdd(&cnt[coarse[base + i].x >> 18], 1);
    __syncthreads();
    // 1024-wide Hillis-Steele inclusive scan (768 live counters, rest zero)
    int v = (t < 768) ? cnt[t] : 0;
    sm[t] = v;
    __syncthreads();
    for (int o = 1; o < 1024; o <<= 1) {
        int add = (t >= o) ? sm[t - o] : 0;
        __syncthreads();
        sm[t] += add;
        __syncthreads();
    }
    if (t < 768) rs[t] = sm[t] - v;   // exclusive prefix within bucket
    __syncthreads();
    int nodes0 = k * NPB;
    int nb = min(NPB, N_NODES - nodes0);
    if (t < nb)
        rowinfo[nodes0 + t] = (uint)(base + rs[t]) | ((uint)cnt[t] << 22);
    __syncthreads();
    if (t < 768) cnt[t] = rs[t];      // cnt becomes cursor
    __syncthreads();
    for (int i = t; i < ne; i += 1024) {
        int2 ev = coarse[base + i];
        int dl = ev.x >> 18;
        int p = atomicAdd(&cnt[dl], 1);
        epair[base + p] = make_int2(ev.x & 0x3FFFF, ev.y);
    }
}

// SpMM over bf16 rows (32 uints = 128B/row). One wave per node; 4 groups x
// 16 lanes; 4x unrolled -> 16 edges in flight. Lane l holds uint2 = dims
// [4l..4l+3]; packed f32 FMA (v2f); 2-round cross-group reduce.
__global__ __launch_bounds__(256) void spmm_kernel(
        const uint* __restrict__ rowinfo, const int2* __restrict__ epair,
        const uint* __restrict__ xin, uint* __restrict__ xout) {
    int n = (blockIdx.x * 256 + threadIdx.x) >> 6;   // 150000 = 4*37500 exact
    int lane = threadIdx.x & 63;
    int g = lane >> 4;        // edge group 0..3
    int l = lane & 15;        // uint2 slot within row
    uint ri = rowinfo[n];
    int s = (int)(ri & 0x3FFFFFu);
    int e = s + (int)(ri >> 22);
    v2f a0 = {0.f, 0.f}, a1 = {0.f, 0.f};
    for (int j0 = s + g; j0 < e; j0 += 16) {
        int2 ev[4];
        float vv[4];
        uint2 rr[4];
#pragma unroll
        for (int u = 0; u < 4; ++u) {
            int j = j0 + 4 * u;
            bool p = (u == 0) || (j < e);
            ev[u] = epair[p ? j : j0];
            vv[u] = p ? __int_as_float(ev[u].y) : 0.f;
        }
#pragma unroll
        for (int u = 0; u < 4; ++u)
            rr[u] = ((const uint2*)(xin + (size_t)ev[u].x * 32))[l];
#pragma unroll
        for (int u = 0; u < 4; ++u) {
            a0 += vv[u] * unpack_bf16x2(rr[u].x);
            a1 += vv[u] * unpack_bf16x2(rr[u].y);
        }
    }
#pragma unroll
    for (int off = 16; off < 64; off <<= 1) {
        a0.x += __shfl_xor(a0.x, off, 64);
        a0.y += __shfl_xor(a0.y, off, 64);
        a1.x += __shfl_xor(a1.x, off, 64);
        a1.y += __shfl_xor(a1.y, off, 64);
    }
    if (g == 0) {
        uint2 o;
        o.x = pack_bf16(a0.x, a0.y);
        o.y = pack_bf16(a1.x, a1.y);
        ((uint2*)(xout + (size_t)n * 32))[l] = o;
    }
}

// Fused epilogue: one wave per batch element, lane = dim.
// gamma[b] = dot(x0u+x1u+x2u+x3u, x0i+x1i+x2i+x3i) / 16
__global__ __launch_bounds__(256) void final_kernel(
        const int* __restrict__ users, const int* __restrict__ items,
        const float* __restrict__ emb_user, const float* __restrict__ emb_item,
        const unsigned short* __restrict__ x1, const unsigned short* __restrict__ x2,
        const unsigned short* __restrict__ x3, float* __restrict__ out) {
    int t = blockIdx.x * 256 + threadIdx.x;
    int b = t >> 6;
    int lane = t & 63;
    int un = users[b];
    int in = N_USERS + items[b];
    size_t uo = (size_t)un * DIM + lane;
    size_t io = (size_t)in * DIM + lane;
    float u = emb_user[uo]
            + __uint_as_float((uint)x1[uo] << 16)
            + __uint_as_float((uint)x2[uo] << 16)
            + __uint_as_float((uint)x3[uo] << 16);
    float v = emb_item[(size_t)items[b] * DIM + lane]
            + __uint_as_float((uint)x1[io] << 16)
            + __uint_as_float((uint)x2[io] << 16)
            + __uint_as_float((uint)x3[io] << 16);
    float p = u * v;
#pragma unroll
    for (int o = 32; o > 0; o >>= 1) p += __shfl_down(p, o, 64);
    if (lane == 0) out[b] = p * (1.0f / 16.0f);
}

extern "C" void kernel_launch(void* const* d_in, const int* in_sizes, int n_in,
                              void* d_out, int out_size, void* d_ws, size_t ws_size,
                              hipStream_t stream) {
    const float* emb_user = (const float*)d_in[0];
    const float* emb_item = (const float*)d_in[1];
    const float* vals     = (const float*)d_in[2];
    const int*   src      = (const int*)d_in[3];
    const int*   dst      = (const int*)d_in[4];
    const int*   users    = (const int*)d_in[5];
    const int*   items    = (const int*)d_in[6];
    float* out = (float*)d_out;

    char* ws = (char*)d_ws;
    size_t off = 0;
    auto walloc = [&](size_t bytes) -> void* {
        void* p = ws + off;
        off += (bytes + 255) & ~(size_t)255;
        return p;
    };
    const size_t ROWB = (size_t)N_NODES * DIM * 2;                  // 19.2 MB
    uint* t0         = (uint*)walloc(ROWB);                         // bf16 x0
    uint* x1         = (uint*)walloc(ROWB);
    uint* x2         = (uint*)walloc(ROWB);
    uint* x3         = (uint*)walloc(ROWB);                         // aliases coarse
    int2* epair      = (int2*)walloc((size_t)N_EDGES * 8);          // 19.2 MB
    int*  hist       = (int*) walloc((size_t)CHUNKS * KB * 4);      // 0.5 MB
    int*  tot        = (int*) walloc((size_t)KB * 4);
    uint* rowinfo    = (uint*)walloc((size_t)N_NODES * 4);
    // coarse (N_EDGES*8 = 19.2 MB) aliases x3: dead once p4 completes,
    // x3 first written by SpMM layer 3 (after p4). Sizes are exactly equal.
    int2* coarse = (int2*)x3;

    // CSR build (+ fused bf16 conversion)
    p1_hist_conv<<<CHUNKS + CONVB, 256, 0, stream>>>(dst, hist, emb_user, emb_item, (uint2*)t0);
    p2a_scan<<<KB, 256, 0, stream>>>(hist, tot);
    p3_part<<<CHUNKS, 256, 0, stream>>>(src, dst, vals, hist, tot, coarse);
    p4_fine<<<KB, 1024, 0, stream>>>(coarse, tot, epair, rowinfo);

    int sblocks = N_NODES / 4;  // 37500
    spmm_kernel<<<sblocks, 256, 0, stream>>>(rowinfo, epair, t0, x1);
    spmm_kernel<<<sblocks, 256, 0, stream>>>(rowinfo, epair, x1, x2);
    spmm_kernel<<<sblocks, 256, 0, stream>>>(rowinfo, epair, x2, x3);

    // fused epilogue
    final_kernel<<<(BATCH * DIM) / 256, 256, 0, stream>>>(
        users, items, emb_user, emb_item,
        (const unsigned short*)x1, (const unsigned short*)x2, (const unsigned short*)x3, out);
}